// Round 12
// baseline (514.531 us; speedup 1.0000x reference)
//
#include <hip/hip_runtime.h>

#define DIM 64
#define BIN_SHIFT 8          // 256 nodes per bin
#define BCAP 5120            // staging capacity per bin (mean 4096, +16 sigma)

typedef __attribute__((ext_vector_type(8))) _Float16 half8;
typedef __attribute__((ext_vector_type(4))) _Float16 half4;
typedef __attribute__((ext_vector_type(4))) float floatx4;

// ---------------------------------------------------------------------------
// Pass A: bin edges by col>>8 into per-bin staging with chunk reservation.
// ---------------------------------------------------------------------------
__launch_bounds__(256)
__global__ void bin_edges_kernel(const int* __restrict__ row,
                                 const int* __restrict__ col,
                                 int* __restrict__ bin_cursor,
                                 int2* __restrict__ staging, int E) {
    __shared__ int hist[512];
    __shared__ int base[512];
    int tid = threadIdx.x;
    for (int i = tid; i < 512; i += 256) hist[i] = 0;
    __syncthreads();
    int e0 = blockIdx.x * 4096;
    int c[16];
    #pragma unroll
    for (int k = 0; k < 16; ++k) {
        int e = e0 + tid + k * 256;
        c[k] = (e < E) ? col[e] : -1;
        if (c[k] >= 0) atomicAdd(&hist[c[k] >> BIN_SHIFT], 1);
    }
    __syncthreads();
    for (int i = tid; i < 512; i += 256) {
        base[i] = (hist[i] > 0) ? atomicAdd(&bin_cursor[i], hist[i]) : 0;
        hist[i] = 0;   // reuse as intra-block offset
    }
    __syncthreads();
    #pragma unroll
    for (int k = 0; k < 16; ++k) {
        if (c[k] >= 0) {
            int e = e0 + tid + k * 256;
            int b = c[k] >> BIN_SHIFT;
            int idx = atomicAdd(&hist[b], 1);
            staging[(size_t)b * BCAP + base[b] + idx] = make_int2(row[e], c[k]);
        }
    }
}

// ---------------------------------------------------------------------------
// Per-bin degree count + dinv/rdinv (contiguous traffic, LDS atomics only).
// ---------------------------------------------------------------------------
__launch_bounds__(256)
__global__ void count_deg_bins_kernel(const int2* __restrict__ staging,
                                      const int* __restrict__ bin_cursor,
                                      int* __restrict__ deg,
                                      float* __restrict__ dinv,
                                      float* __restrict__ rdinv, int N) {
    __shared__ int hist[256];
    int b = blockIdx.x;
    int tid = threadIdx.x;
    hist[tid] = 0;
    __syncthreads();
    int cnt = bin_cursor[b];
    for (int i = tid; i < cnt; i += 256)
        atomicAdd(&hist[staging[(size_t)b * BCAP + i].y & 255], 1);
    __syncthreads();
    int n = (b << BIN_SHIFT) + tid;
    if (n < N) {
        int dg = hist[tid];
        deg[n] = dg;
        float d = (float)dg + 1.0f;
        dinv[n] = rsqrtf(d);
        rdinv[n] = sqrtf(d);
    }
}

// --------------------------- exclusive scan over PADDED degree -------------
// pdeg = (deg+7)&~7 so every CSC bucket is a multiple of 8 edges.
__global__ void reduce_chunks_kernel(const int* __restrict__ deg,
                                     int* __restrict__ bs, int N) {
    __shared__ int s[256];
    int t = threadIdx.x;
    int i = blockIdx.x * 256 + t;
    s[t] = (i < N) ? ((deg[i] + 7) & ~7) : 0;
    __syncthreads();
    for (int d = 128; d > 0; d >>= 1) {
        if (t < d) s[t] += s[t + d];
        __syncthreads();
    }
    if (t == 0) bs[blockIdx.x] = s[0];
}

__global__ void scan_block_sums_kernel(int* __restrict__ bs, int nb) {
    __shared__ int s[1024];
    int t = threadIdx.x;
    s[t] = (t < nb) ? bs[t] : 0;
    __syncthreads();
    for (int d = 1; d < 1024; d <<= 1) {
        int v = (t >= d) ? s[t - d] : 0;
        __syncthreads();
        s[t] += v;
        __syncthreads();
    }
    if (t < nb) bs[t] = (t == 0) ? 0 : s[t - 1];
}

__global__ void scan_chunks_kernel(const int* __restrict__ deg,
                                   const int* __restrict__ bs,
                                   int* __restrict__ ptr, int N) {
    __shared__ int s[256];
    int b = blockIdx.x, t = threadIdx.x;
    int i = b * 256 + t;
    int v = (i < N) ? ((deg[i] + 7) & ~7) : 0;
    s[t] = v;
    __syncthreads();
    for (int d = 1; d < 256; d <<= 1) {
        int u = (t >= d) ? s[t - d] : 0;
        __syncthreads();
        s[t] += u;
        __syncthreads();
    }
    if (i < N) {
        int p = bs[b] + s[t] - v;
        ptr[i] = p;
        if (i == N - 1) ptr[N] = p + v;
    }
}

// ---------------------------------------------------------------------------
// Pass B: one block per bin; LDS cursors; pads buckets (to x8) with dummy N.
// ---------------------------------------------------------------------------
__launch_bounds__(256)
__global__ void fill_bins_kernel(const int2* __restrict__ staging,
                                 const int* __restrict__ bin_cursor,
                                 const int* __restrict__ ptr,
                                 int* __restrict__ srcs, int N, int dummy) {
    __shared__ int cur[256];
    int b = blockIdx.x;
    int tid = threadIdx.x;
    int n = (b << BIN_SHIFT) + tid;
    cur[tid] = (n < N) ? ptr[n] : 0;
    __syncthreads();
    int cnt = bin_cursor[b];
    for (int i = tid; i < cnt; i += 256) {
        int2 rc = staging[(size_t)b * BCAP + i];
        int pos = atomicAdd(&cur[rc.y & 255], 1);
        srcs[pos] = rc.x;
    }
    __syncthreads();
    if (n < N) {
        int e = cur[tid];            // == ptr[n] + deg[n]
        int stop = ptr[n + 1];
        for (; e < stop; ++e) srcs[e] = dummy;
    }
}

// ---------------------------------------------------------------------------
// scale_init: v0 (slab-major fp16, = dinv*x) and x16 (row-major fp16 copy).
// ---------------------------------------------------------------------------
__global__ void scale_init_slab_kernel(const float* __restrict__ x,
                                       const float* __restrict__ dinv,
                                       _Float16* __restrict__ v0,
                                       _Float16* __restrict__ x16, int N) {
    int t = blockIdx.x * blockDim.x + threadIdx.x;
    if (t < N * 16) {
        int n = t >> 4, d4 = (t & 15) * 4;
        float d = dinv[n];
        float4 a = *(const float4*)(x + (size_t)n * DIM + d4);
        half4 hx;
        hx.x = (_Float16)a.x; hx.y = (_Float16)a.y;
        hx.z = (_Float16)a.z; hx.w = (_Float16)a.w;
        *(half4*)(x16 + (size_t)n * DIM + d4) = hx;
        half4 hv;
        hv.x = (_Float16)(a.x * d); hv.y = (_Float16)(a.y * d);
        hv.z = (_Float16)(a.z * d); hv.w = (_Float16)(a.w * d);
        int slab = d4 >> 4, off = d4 & 15;
        *(half4*)(v0 + ((size_t)slab * (N + 1) + n) * 16 + off) = hv;
    }
}

// zero dummy row (n=N) of all 6 slab-major buffers x 4 slabs
__global__ void zero_dummy_kernel(_Float16* v0, _Float16* v1, _Float16* v3,
                                  _Float16* v7, _Float16* T1, _Float16* T2,
                                  int N) {
    _Float16* bufs[6] = {v0, v1, v3, v7, T1, T2};
    int t = threadIdx.x;
    for (int i = t; i < 6 * 64; i += 256) {
        int b = i >> 6, r = i & 63;
        int slab = r >> 4, d = r & 15;
        bufs[b][((size_t)slab * (N + 1) + N) * 16 + d] = (_Float16)0.f;
    }
}

// ---------------------------------------------------------------------------
// Slab-major v-space propagate. One dispatch covers all 4 slabs (blockIdx
// partition); each slab's gather working set is 3.2 MB -> per-XCD L2
// resident. Wave = 4 nodes; per quarter: 8 edge slots x 2 half8 lanes.
// Buckets padded to x8 (dummy -> zero row). Fold via shfl_xor 2/4/8.
// ---------------------------------------------------------------------------
__launch_bounds__(256)
__global__ void spmv_slab_kernel(const int* __restrict__ ptr,
                                 const int* __restrict__ srcs,
                                 const float* __restrict__ dinv,
                                 const _Float16* __restrict__ vin,
                                 _Float16* __restrict__ vout,
                                 int N, int bps) {
    int slab = blockIdx.x / bps;
    int blk  = blockIdx.x - slab * bps;
    const _Float16* vi = vin + (size_t)slab * (N + 1) * 16;
    _Float16* vo = vout + (size_t)slab * (N + 1) * 16;
    int tid = threadIdx.x;
    int lane = tid & 63;
    int q = lane >> 4;            // node sub-slot 0..3
    int e2 = (lane >> 1) & 7;     // edge slot 0..7
    int h = lane & 1;             // 16B half of the 32B row
    int n = (blk * 4 + (tid >> 6)) * 4 + q;
    bool valid = n < N;
    int beg = valid ? ptr[n] : 0;
    int end = valid ? ptr[n + 1] : 0;

    float a[8];
    #pragma unroll
    for (int k = 0; k < 8; ++k) a[k] = 0.f;

    #pragma unroll 2
    for (int j = beg; j < end; j += 8) {
        int s = srcs[j + e2];
        half8 hv = *(const half8*)(vi + ((size_t)s << 4) + (h << 3));
        #pragma unroll
        for (int k = 0; k < 8; ++k) a[k] += (float)hv[k];
    }
    #pragma unroll
    for (int k = 0; k < 8; ++k) {
        a[k] += __shfl_xor(a[k], 2);
        a[k] += __shfl_xor(a[k], 4);
        a[k] += __shfl_xor(a[k], 8);
    }
    if (e2 == 0 && valid) {
        half8 hs = *(const half8*)(vi + ((size_t)n << 4) + (h << 3));
        float d = dinv[n];
        float dd = d * d;
        half8 r;
        #pragma unroll
        for (int k = 0; k < 8; ++k)
            r[k] = (_Float16)(dd * (a[k] + (float)hs[k]));
        *(half8*)(vo + ((size_t)n << 4) + (h << 3)) = r;
    }
}

// ---------------------------------------------------------------------------
// Reference quirk: r never updates -> powers cumulative:
//   x_agg[1] = A x, x_agg[2] = A^3 x, x_agg[4] = A^7 x.
//   cat@W = x@W3 + p1@(W0-W3+W4) + p3@(W1-W4+W5) + p7@(W2-W5)
// ---------------------------------------------------------------------------
__global__ void make_weff_kernel(const float* __restrict__ W,
                                 float* __restrict__ weff) {
    int t = blockIdx.x * blockDim.x + threadIdx.x;
    if (t < 64 * 64) {
        int k = t >> 6, d = t & 63;
        float w0 = W[(0 * 64 + k) * 64 + d];
        float w1 = W[(1 * 64 + k) * 64 + d];
        float w2 = W[(2 * 64 + k) * 64 + d];
        float w3 = W[(3 * 64 + k) * 64 + d];
        float w4 = W[(4 * 64 + k) * 64 + d];
        float w5 = W[(5 * 64 + k) * 64 + d];
        weff[(0 * 64 + k) * 64 + d] = w3;
        weff[(1 * 64 + k) * 64 + d] = w0 - w3 + w4;
        weff[(2 * 64 + k) * 64 + d] = w1 - w4 + w5;
        weff[(3 * 64 + k) * 64 + d] = w2 - w5;
    }
}

// ---------------------------------------------------------------------------
// MFMA combine v2: B (4 dim-tiles x 8 k-steps) held in VGPRs (one-time LDS
// transpose); A-fragments loaded DIRECTLY from global in MFMA A-layout
// (half8), rdinv applied as fp16 scale. One wave = one 16-node group, all
// 64 output dims (32 mfma). No per-group LDS traffic.
// Verified layouts: A/B row = lane&15, k = quad*8+j; D col=lane&15,
// row=quad*4+reg.
// ---------------------------------------------------------------------------
__launch_bounds__(256, 2)
__global__ void combine_mfma_kernel(const _Float16* __restrict__ x16,
                                    const _Float16* __restrict__ v1,
                                    const _Float16* __restrict__ v3,
                                    const _Float16* __restrict__ v7,
                                    const float* __restrict__ rdinv,
                                    const float* __restrict__ weff,
                                    const float* __restrict__ bias,
                                    float* __restrict__ out, int N) {
    __shared__ _Float16 sWt[64][264];  // [dim][kk] transposed f16 W
    int tid = threadIdx.x;
    for (int i = tid; i < 64 * 256; i += 256) {
        int kk = i >> 6, d = i & 63;
        sWt[d][kk] = (_Float16)weff[i];
    }
    __syncthreads();
    int lane = tid & 63, w = tid >> 6;
    int quad = lane >> 4, col = lane & 15;

    half8 br[4][8];
    #pragma unroll
    for (int dt = 0; dt < 4; ++dt)
        #pragma unroll
        for (int t = 0; t < 8; ++t)
            br[dt][t] = *(const half8*)&sWt[dt * 16 + col][t * 32 + quad * 8];
    float bv[4];
    #pragma unroll
    for (int dt = 0; dt < 4; ++dt) bv[dt] = bias[dt * 16 + col];

    int bps = (N + 15) / 16;
    size_t N1 = (size_t)N + 1;
    for (int g = blockIdx.x * 4 + w; g < bps; g += gridDim.x * 4) {
        int n0 = g * 16;
        int n = n0 + col;
        int nl = (n < N) ? n : 0;
        _Float16 hrd = (_Float16)rdinv[nl];

        half8 a[8];
        a[0] = *(const half8*)(x16 + (size_t)nl * DIM + quad * 8);
        a[1] = *(const half8*)(x16 + (size_t)nl * DIM + 32 + quad * 8);
        const _Float16* vs[3] = {v1, v3, v7};
        #pragma unroll
        for (int sI = 0; sI < 3; ++sI) {
            #pragma unroll
            for (int hf = 0; hf < 2; ++hf) {
                int d0 = hf * 32 + quad * 8;
                int slab = d0 >> 4, off = d0 & 15;
                half8 hv = *(const half8*)(vs[sI] + ((size_t)slab * N1 + nl) * 16 + off);
                #pragma unroll
                for (int j = 0; j < 8; ++j) hv[j] = hv[j] * hrd;
                a[2 + sI * 2 + hf] = hv;
            }
        }

        floatx4 acc[4];
        #pragma unroll
        for (int dt = 0; dt < 4; ++dt) {
            floatx4 z = {bv[dt], bv[dt], bv[dt], bv[dt]};
            acc[dt] = z;
        }
        #pragma unroll
        for (int t = 0; t < 8; ++t)
            #pragma unroll
            for (int dt = 0; dt < 4; ++dt)
                acc[dt] = __builtin_amdgcn_mfma_f32_16x16x32_f16(
                    a[t], br[dt][t], acc[dt], 0, 0, 0);

        #pragma unroll
        for (int dt = 0; dt < 4; ++dt)
            #pragma unroll
            for (int r = 0; r < 4; ++r) {
                int nn = n0 + quad * 4 + r;
                if (nn < N)
                    out[(size_t)nn * DIM + dt * 16 + col] =
                        fmaxf(acc[dt][r], 0.f);
            }
    }
}

extern "C" void kernel_launch(void* const* d_in, const int* in_sizes, int n_in,
                              void* d_out, int out_size, void* d_ws, size_t ws_size,
                              hipStream_t stream) {
    const float* x  = (const float*)d_in[0];
    const int*   ei = (const int*)d_in[1];
    const float* W  = (const float*)d_in[2];
    const float* b  = (const float*)d_in[3];
    float* out = (float*)d_out;

    const int N = in_sizes[0] / DIM;
    const int E = in_sizes[1] / 2;
    const int* row = ei;
    const int* col = ei + E;

    const int nbins = (N + 255) >> BIN_SHIFT;
    const int bps = (N + 15) / 16;        // blocks per slab for spmv
    const size_t SLABSZ = (size_t)4 * (N + 1) * 16;   // halves per buffer

    int2* staging = (int2*)d_ws;                          // 512*BCAP
    float* dinv  = (float*)(staging + (size_t)512 * BCAP);
    float* rdinv = dinv + N;
    float* weff  = rdinv + N;                             // 16384
    _Float16* x16 = (_Float16*)(weff + 16384);            // (N+16)*64
    _Float16* v0 = x16 + (size_t)(N + 16) * 64;
    _Float16* v1 = v0 + SLABSZ;
    _Float16* v3 = v1 + SLABSZ;
    _Float16* v7 = v3 + SLABSZ;
    _Float16* T1 = v7 + SLABSZ;
    _Float16* T2 = T1 + SLABSZ;
    int* deg = (int*)(T2 + SLABSZ);       // N
    int* ptr = deg + N;                   // N+1
    int* bs  = ptr + N + 1;               // <=1024
    int* bin_cursor = bs + 1024;          // 512
    int* srcs = bin_cursor + 512;         // E + 7N

    const int nb = (N + 255) / 256;

    // --- bin edges ---
    hipMemsetAsync(bin_cursor, 0, 512 * sizeof(int), stream);
    bin_edges_kernel<<<(E + 4095) / 4096, 256, 0, stream>>>(row, col,
                                                            bin_cursor,
                                                            staging, E);
    // --- per-bin degree + dinv/rdinv ---
    count_deg_bins_kernel<<<nbins, 256, 0, stream>>>(staging, bin_cursor,
                                                     deg, dinv, rdinv, N);
    // --- exclusive scan of padded deg -> ptr ---
    reduce_chunks_kernel<<<nb, 256, 0, stream>>>(deg, bs, N);
    scan_block_sums_kernel<<<1, 1024, 0, stream>>>(bs, nb);
    scan_chunks_kernel<<<nb, 256, 0, stream>>>(deg, bs, ptr, N);
    // --- CSC fill from bins (pads to x8 with dummy N) ---
    fill_bins_kernel<<<nbins, 256, 0, stream>>>(staging, bin_cursor, ptr,
                                                srcs, N, N);
    // --- effective W ---
    make_weff_kernel<<<16, 256, 0, stream>>>(W, weff);

    // --- v0 (slab-major) + x16; zero dummy rows ---
    scale_init_slab_kernel<<<(N * 16 + 255) / 256, 256, 0, stream>>>(x, dinv,
                                                                     v0, x16, N);
    zero_dummy_kernel<<<1, 256, 0, stream>>>(v0, v1, v3, v7, T1, T2, N);

    auto prop = [&](const _Float16* src, _Float16* dst) {
        spmv_slab_kernel<<<4 * bps, 256, 0, stream>>>(ptr, srcs, dinv,
                                                      src, dst, N, bps);
    };
    prop(v0, v1);   // A^1
    prop(v1, T1);   // A^2
    prop(T1, v3);   // A^3
    prop(v3, T1);   // A^4
    prop(T1, T2);   // A^5
    prop(T2, T1);   // A^6
    prop(T1, v7);   // A^7

    // --- combine (MFMA, B-in-VGPR, direct A loads) ---
    combine_mfma_kernel<<<512, 256, 0, stream>>>(x16, v1, v3, v7, rdinv,
                                                 weff, b, out, N);
}

// Round 13
// 494.031 us; speedup vs baseline: 1.0415x; 1.0415x over previous
//
#include <hip/hip_runtime.h>

#define DIM 64
#define BIN_SHIFT 8          // 256 nodes per bin
#define BCAP 5120            // staging capacity per bin (mean 4096, +16 sigma)

typedef __attribute__((ext_vector_type(8))) _Float16 half8;
typedef __attribute__((ext_vector_type(4))) _Float16 half4;
typedef __attribute__((ext_vector_type(4))) float floatx4;

// ---------------------------------------------------------------------------
// Pass A: bin edges by col>>8 into per-bin staging with chunk reservation.
// ---------------------------------------------------------------------------
__launch_bounds__(256)
__global__ void bin_edges_kernel(const int* __restrict__ row,
                                 const int* __restrict__ col,
                                 int* __restrict__ bin_cursor,
                                 int2* __restrict__ staging, int E) {
    __shared__ int hist[512];
    __shared__ int base[512];
    int tid = threadIdx.x;
    for (int i = tid; i < 512; i += 256) hist[i] = 0;
    __syncthreads();
    int e0 = blockIdx.x * 4096;
    int c[16];
    #pragma unroll
    for (int k = 0; k < 16; ++k) {
        int e = e0 + tid + k * 256;
        c[k] = (e < E) ? col[e] : -1;
        if (c[k] >= 0) atomicAdd(&hist[c[k] >> BIN_SHIFT], 1);
    }
    __syncthreads();
    for (int i = tid; i < 512; i += 256) {
        base[i] = (hist[i] > 0) ? atomicAdd(&bin_cursor[i], hist[i]) : 0;
        hist[i] = 0;   // reuse as intra-block offset
    }
    __syncthreads();
    #pragma unroll
    for (int k = 0; k < 16; ++k) {
        if (c[k] >= 0) {
            int e = e0 + tid + k * 256;
            int b = c[k] >> BIN_SHIFT;
            int idx = atomicAdd(&hist[b], 1);
            staging[(size_t)b * BCAP + base[b] + idx] = make_int2(row[e], c[k]);
        }
    }
}

// ---------------------------------------------------------------------------
// Per-bin degree count + dinv/rdinv (contiguous traffic, LDS atomics only).
// ---------------------------------------------------------------------------
__launch_bounds__(256)
__global__ void count_deg_bins_kernel(const int2* __restrict__ staging,
                                      const int* __restrict__ bin_cursor,
                                      int* __restrict__ deg,
                                      float* __restrict__ dinv,
                                      float* __restrict__ rdinv, int N) {
    __shared__ int hist[256];
    int b = blockIdx.x;
    int tid = threadIdx.x;
    hist[tid] = 0;
    __syncthreads();
    int cnt = bin_cursor[b];
    for (int i = tid; i < cnt; i += 256)
        atomicAdd(&hist[staging[(size_t)b * BCAP + i].y & 255], 1);
    __syncthreads();
    int n = (b << BIN_SHIFT) + tid;
    if (n < N) {
        int dg = hist[tid];
        deg[n] = dg;
        float d = (float)dg + 1.0f;
        dinv[n] = rsqrtf(d);
        rdinv[n] = sqrtf(d);
    }
}

// --------------------------- exclusive scan over PADDED degree -------------
// pdeg = (deg+7)&~7 so every CSC bucket is a multiple of 8 edges.
__global__ void reduce_chunks_kernel(const int* __restrict__ deg,
                                     int* __restrict__ bs, int N) {
    __shared__ int s[256];
    int t = threadIdx.x;
    int i = blockIdx.x * 256 + t;
    s[t] = (i < N) ? ((deg[i] + 7) & ~7) : 0;
    __syncthreads();
    for (int d = 128; d > 0; d >>= 1) {
        if (t < d) s[t] += s[t + d];
        __syncthreads();
    }
    if (t == 0) bs[blockIdx.x] = s[0];
}

__global__ void scan_block_sums_kernel(int* __restrict__ bs, int nb) {
    __shared__ int s[1024];
    int t = threadIdx.x;
    s[t] = (t < nb) ? bs[t] : 0;
    __syncthreads();
    for (int d = 1; d < 1024; d <<= 1) {
        int v = (t >= d) ? s[t - d] : 0;
        __syncthreads();
        s[t] += v;
        __syncthreads();
    }
    if (t < nb) bs[t] = (t == 0) ? 0 : s[t - 1];
}

__global__ void scan_chunks_kernel(const int* __restrict__ deg,
                                   const int* __restrict__ bs,
                                   int* __restrict__ ptr, int N) {
    __shared__ int s[256];
    int b = blockIdx.x, t = threadIdx.x;
    int i = b * 256 + t;
    int v = (i < N) ? ((deg[i] + 7) & ~7) : 0;
    s[t] = v;
    __syncthreads();
    for (int d = 1; d < 256; d <<= 1) {
        int u = (t >= d) ? s[t - d] : 0;
        __syncthreads();
        s[t] += u;
        __syncthreads();
    }
    if (i < N) {
        int p = bs[b] + s[t] - v;
        ptr[i] = p;
        if (i == N - 1) ptr[N] = p + v;
    }
}

// ---------------------------------------------------------------------------
// Pass B: one block per bin; LDS cursors; pads buckets (to x8) with dummy N.
// ---------------------------------------------------------------------------
__launch_bounds__(256)
__global__ void fill_bins_kernel(const int2* __restrict__ staging,
                                 const int* __restrict__ bin_cursor,
                                 const int* __restrict__ ptr,
                                 int* __restrict__ srcs, int N, int dummy) {
    __shared__ int cur[256];
    int b = blockIdx.x;
    int tid = threadIdx.x;
    int n = (b << BIN_SHIFT) + tid;
    cur[tid] = (n < N) ? ptr[n] : 0;
    __syncthreads();
    int cnt = bin_cursor[b];
    for (int i = tid; i < cnt; i += 256) {
        int2 rc = staging[(size_t)b * BCAP + i];
        int pos = atomicAdd(&cur[rc.y & 255], 1);
        srcs[pos] = rc.x;
    }
    __syncthreads();
    if (n < N) {
        int e = cur[tid];            // == ptr[n] + deg[n]
        int stop = ptr[n + 1];
        for (; e < stop; ++e) srcs[e] = dummy;
    }
}

// ---------------------------------------------------------------------------
// scale_init: v0 (slab-major fp16, = dinv*x) and x16 (row-major fp16 copy).
// ---------------------------------------------------------------------------
__global__ void scale_init_slab_kernel(const float* __restrict__ x,
                                       const float* __restrict__ dinv,
                                       _Float16* __restrict__ v0,
                                       _Float16* __restrict__ x16, int N) {
    int t = blockIdx.x * blockDim.x + threadIdx.x;
    if (t < N * 16) {
        int n = t >> 4, d4 = (t & 15) * 4;
        float d = dinv[n];
        float4 a = *(const float4*)(x + (size_t)n * DIM + d4);
        half4 hx;
        hx.x = (_Float16)a.x; hx.y = (_Float16)a.y;
        hx.z = (_Float16)a.z; hx.w = (_Float16)a.w;
        *(half4*)(x16 + (size_t)n * DIM + d4) = hx;
        half4 hv;
        hv.x = (_Float16)(a.x * d); hv.y = (_Float16)(a.y * d);
        hv.z = (_Float16)(a.z * d); hv.w = (_Float16)(a.w * d);
        int slab = d4 >> 4, off = d4 & 15;
        *(half4*)(v0 + ((size_t)slab * (N + 1) + n) * 16 + off) = hv;
    }
}

// zero dummy row (n=N) of all 6 slab-major buffers x 4 slabs
__global__ void zero_dummy_kernel(_Float16* v0, _Float16* v1, _Float16* v3,
                                  _Float16* v7, _Float16* T1, _Float16* T2,
                                  int N) {
    _Float16* bufs[6] = {v0, v1, v3, v7, T1, T2};
    int t = threadIdx.x;
    for (int i = t; i < 6 * 64; i += 256) {
        int b = i >> 6, r = i & 63;
        int slab = r >> 4, d = r & 15;
        bufs[b][((size_t)slab * (N + 1) + N) * 16 + d] = (_Float16)0.f;
    }
}

// ---------------------------------------------------------------------------
// Slab-major v-space propagate with XCD-pinned slabs: assuming the standard
// round-robin block->XCD mapping (xcd = blockIdx%8), slab = (blockIdx&7)>>1
// pins slab s to XCD pair {2s,2s+1}; per-XCD gather working set = 3.2 MB
// < 4 MiB L2 -> gathers become L2 hits. Wave = 4 nodes; per quarter: 8 edge
// slots x 2 half8 lanes. Buckets padded to x8 (dummy -> zero row).
// ---------------------------------------------------------------------------
__launch_bounds__(256)
__global__ void spmv_slab_kernel(const int* __restrict__ ptr,
                                 const int* __restrict__ srcs,
                                 const float* __restrict__ dinv,
                                 const _Float16* __restrict__ vin,
                                 _Float16* __restrict__ vout,
                                 int N, int bps) {
    int b = blockIdx.x;
    int slab = (b & 7) >> 1;                 // XCD pair -> slab
    int blk  = ((b >> 3) << 1) | (b & 1);    // index within slab
    if (blk >= bps) return;
    const _Float16* vi = vin + (size_t)slab * (N + 1) * 16;
    _Float16* vo = vout + (size_t)slab * (N + 1) * 16;
    int tid = threadIdx.x;
    int lane = tid & 63;
    int q = lane >> 4;            // node sub-slot 0..3
    int e2 = (lane >> 1) & 7;     // edge slot 0..7
    int h = lane & 1;             // 16B half of the 32B row
    int n = (blk * 4 + (tid >> 6)) * 4 + q;
    bool valid = n < N;
    int beg = valid ? ptr[n] : 0;
    int end = valid ? ptr[n + 1] : 0;

    float a[8];
    #pragma unroll
    for (int k = 0; k < 8; ++k) a[k] = 0.f;

    #pragma unroll 2
    for (int j = beg; j < end; j += 8) {
        int s = srcs[j + e2];
        half8 hv = *(const half8*)(vi + ((size_t)s << 4) + (h << 3));
        #pragma unroll
        for (int k = 0; k < 8; ++k) a[k] += (float)hv[k];
    }
    #pragma unroll
    for (int k = 0; k < 8; ++k) {
        a[k] += __shfl_xor(a[k], 2);
        a[k] += __shfl_xor(a[k], 4);
        a[k] += __shfl_xor(a[k], 8);
    }
    if (e2 == 0 && valid) {
        half8 hs = *(const half8*)(vi + ((size_t)n << 4) + (h << 3));
        float d = dinv[n];
        float dd = d * d;
        half8 r;
        #pragma unroll
        for (int k = 0; k < 8; ++k)
            r[k] = (_Float16)(dd * (a[k] + (float)hs[k]));
        *(half8*)(vo + ((size_t)n << 4) + (h << 3)) = r;
    }
}

// ---------------------------------------------------------------------------
// Reference quirk: r never updates -> powers cumulative:
//   x_agg[1] = A x, x_agg[2] = A^3 x, x_agg[4] = A^7 x.
//   cat@W = x@W3 + p1@(W0-W3+W4) + p3@(W1-W4+W5) + p7@(W2-W5)
// ---------------------------------------------------------------------------
__global__ void make_weff_kernel(const float* __restrict__ W,
                                 float* __restrict__ weff) {
    int t = blockIdx.x * blockDim.x + threadIdx.x;
    if (t < 64 * 64) {
        int k = t >> 6, d = t & 63;
        float w0 = W[(0 * 64 + k) * 64 + d];
        float w1 = W[(1 * 64 + k) * 64 + d];
        float w2 = W[(2 * 64 + k) * 64 + d];
        float w3 = W[(3 * 64 + k) * 64 + d];
        float w4 = W[(4 * 64 + k) * 64 + d];
        float w5 = W[(5 * 64 + k) * 64 + d];
        weff[(0 * 64 + k) * 64 + d] = w3;
        weff[(1 * 64 + k) * 64 + d] = w0 - w3 + w4;
        weff[(2 * 64 + k) * 64 + d] = w1 - w4 + w5;
        weff[(3 * 64 + k) * 64 + d] = w2 - w5;
    }
}

// ---------------------------------------------------------------------------
// MFMA combine v3: A-fragments direct from global (MFMA A-layout half8,
// rdinv applied as fp16 scale); B-fragments read per-use from padded LDS
// (ds_read_b128, conflict-free) -> ~90 VGPRs, no spills. One wave = one
// 16-node group, all 64 output dims (32 mfma).
// Verified layouts: A/B row = lane&15, k = quad*8+j; D col=lane&15,
// row=quad*4+reg.
// ---------------------------------------------------------------------------
__launch_bounds__(256)
__global__ void combine_mfma_kernel(const _Float16* __restrict__ x16,
                                    const _Float16* __restrict__ v1,
                                    const _Float16* __restrict__ v3,
                                    const _Float16* __restrict__ v7,
                                    const float* __restrict__ rdinv,
                                    const float* __restrict__ weff,
                                    const float* __restrict__ bias,
                                    float* __restrict__ out, int N) {
    __shared__ _Float16 sWt[64][264];  // [dim][kk] transposed f16 W (padded)
    int tid = threadIdx.x;
    for (int i = tid; i < 64 * 256; i += 256) {
        int kk = i >> 6, d = i & 63;
        sWt[d][kk] = (_Float16)weff[i];
    }
    __syncthreads();
    int lane = tid & 63, w = tid >> 6;
    int quad = lane >> 4, col = lane & 15;

    float bv[4];
    #pragma unroll
    for (int dt = 0; dt < 4; ++dt) bv[dt] = bias[dt * 16 + col];

    int bps = (N + 15) / 16;
    size_t N1 = (size_t)N + 1;
    for (int g = blockIdx.x * 4 + w; g < bps; g += gridDim.x * 4) {
        int n0 = g * 16;
        int n = n0 + col;
        int nl = (n < N) ? n : 0;
        _Float16 hrd = (_Float16)rdinv[nl];

        half8 a[8];
        a[0] = *(const half8*)(x16 + (size_t)nl * DIM + quad * 8);
        a[1] = *(const half8*)(x16 + (size_t)nl * DIM + 32 + quad * 8);
        const _Float16* vs[3] = {v1, v3, v7};
        #pragma unroll
        for (int sI = 0; sI < 3; ++sI) {
            #pragma unroll
            for (int hf = 0; hf < 2; ++hf) {
                int d0 = hf * 32 + quad * 8;
                int slab = d0 >> 4, off = d0 & 15;
                half8 hv = *(const half8*)(vs[sI] + ((size_t)slab * N1 + nl) * 16 + off);
                #pragma unroll
                for (int j = 0; j < 8; ++j) hv[j] = hv[j] * hrd;
                a[2 + sI * 2 + hf] = hv;
            }
        }

        floatx4 acc[4];
        #pragma unroll
        for (int dt = 0; dt < 4; ++dt) {
            floatx4 z = {bv[dt], bv[dt], bv[dt], bv[dt]};
            acc[dt] = z;
        }
        #pragma unroll
        for (int t = 0; t < 8; ++t) {
            #pragma unroll
            for (int dt = 0; dt < 4; ++dt) {
                half8 bf = *(const half8*)&sWt[dt * 16 + col][t * 32 + quad * 8];
                acc[dt] = __builtin_amdgcn_mfma_f32_16x16x32_f16(
                    a[t], bf, acc[dt], 0, 0, 0);
            }
        }

        #pragma unroll
        for (int dt = 0; dt < 4; ++dt)
            #pragma unroll
            for (int r = 0; r < 4; ++r) {
                int nn = n0 + quad * 4 + r;
                if (nn < N)
                    out[(size_t)nn * DIM + dt * 16 + col] =
                        fmaxf(acc[dt][r], 0.f);
            }
    }
}

extern "C" void kernel_launch(void* const* d_in, const int* in_sizes, int n_in,
                              void* d_out, int out_size, void* d_ws, size_t ws_size,
                              hipStream_t stream) {
    const float* x  = (const float*)d_in[0];
    const int*   ei = (const int*)d_in[1];
    const float* W  = (const float*)d_in[2];
    const float* b  = (const float*)d_in[3];
    float* out = (float*)d_out;

    const int N = in_sizes[0] / DIM;
    const int E = in_sizes[1] / 2;
    const int* row = ei;
    const int* col = ei + E;

    const int nbins = (N + 255) >> BIN_SHIFT;
    int bps = (N + 15) / 16;              // blocks per slab for spmv
    if (bps & 1) ++bps;                   // even for the swizzle bijection
    const size_t SLABSZ = (size_t)4 * (N + 1) * 16;   // halves per buffer

    int2* staging = (int2*)d_ws;                          // 512*BCAP
    float* dinv  = (float*)(staging + (size_t)512 * BCAP);
    float* rdinv = dinv + N;
    float* weff  = rdinv + N;                             // 16384
    _Float16* x16 = (_Float16*)(weff + 16384);            // (N+16)*64
    _Float16* v0 = x16 + (size_t)(N + 16) * 64;
    _Float16* v1 = v0 + SLABSZ;
    _Float16* v3 = v1 + SLABSZ;
    _Float16* v7 = v3 + SLABSZ;
    _Float16* T1 = v7 + SLABSZ;
    _Float16* T2 = T1 + SLABSZ;
    int* deg = (int*)(T2 + SLABSZ);       // N
    int* ptr = deg + N;                   // N+1
    int* bs  = ptr + N + 1;               // <=1024
    int* bin_cursor = bs + 1024;          // 512
    int* srcs = bin_cursor + 512;         // E + 7N

    const int nb = (N + 255) / 256;

    // --- bin edges ---
    hipMemsetAsync(bin_cursor, 0, 512 * sizeof(int), stream);
    bin_edges_kernel<<<(E + 4095) / 4096, 256, 0, stream>>>(row, col,
                                                            bin_cursor,
                                                            staging, E);
    // --- per-bin degree + dinv/rdinv ---
    count_deg_bins_kernel<<<nbins, 256, 0, stream>>>(staging, bin_cursor,
                                                     deg, dinv, rdinv, N);
    // --- exclusive scan of padded deg -> ptr ---
    reduce_chunks_kernel<<<nb, 256, 0, stream>>>(deg, bs, N);
    scan_block_sums_kernel<<<1, 1024, 0, stream>>>(bs, nb);
    scan_chunks_kernel<<<nb, 256, 0, stream>>>(deg, bs, ptr, N);
    // --- CSC fill from bins (pads to x8 with dummy N) ---
    fill_bins_kernel<<<nbins, 256, 0, stream>>>(staging, bin_cursor, ptr,
                                                srcs, N, N);
    // --- effective W ---
    make_weff_kernel<<<16, 256, 0, stream>>>(W, weff);

    // --- v0 (slab-major) + x16; zero dummy rows ---
    scale_init_slab_kernel<<<(N * 16 + 255) / 256, 256, 0, stream>>>(x, dinv,
                                                                     v0, x16, N);
    zero_dummy_kernel<<<1, 256, 0, stream>>>(v0, v1, v3, v7, T1, T2, N);

    auto prop = [&](const _Float16* src, _Float16* dst) {
        spmv_slab_kernel<<<4 * bps, 256, 0, stream>>>(ptr, srcs, dinv,
                                                      src, dst, N, bps);
    };
    prop(v0, v1);   // A^1
    prop(v1, T1);   // A^2
    prop(T1, v3);   // A^3
    prop(v3, T1);   // A^4
    prop(T1, T2);   // A^5
    prop(T2, T1);   // A^6
    prop(T1, v7);   // A^7

    // --- combine (MFMA, B from LDS, direct A loads) ---
    combine_mfma_kernel<<<1024, 256, 0, stream>>>(x16, v1, v3, v7, rdinv,
                                                  weff, b, out, N);
}